// Round 8
// baseline (474.801 us; speedup 1.0000x reference)
//
#include <hip/hip_runtime.h>
#include <math.h>

// ---------------------------------------------------------------------------
// Problem constants: B=2, C=64, H=W=D=16, N=4096 positions per batch.
// All tensors fp32. Channel-major layout (B,C,N) unless noted "_cl" (B,N,C).
// ---------------------------------------------------------------------------

// ---------------- weight repack kernels ----------------
// repackA: dst[c][t][o] = src[o][c][t]   (for direct 3x3x3 convs)
__global__ __launch_bounds__(256) void repackA_kernel(const float* __restrict__ src,
                                                      float* __restrict__ dst,
                                                      int M, int total) {
  int i = blockIdx.x * 256 + threadIdx.x;
  if (i >= total) return;
  int o = i % M;
  int t = (i / M) % 27;
  int c = i / (27 * M);
  dst[i] = src[(o * 64 + c) * 27 + t];
}

// repackB: dst[t][c][o] = src[o][c][t]   (for deform einsum, M=64)
__global__ __launch_bounds__(256) void repackB_kernel(const float* __restrict__ src,
                                                      float* __restrict__ dst) {
  int i = blockIdx.x * 256 + threadIdx.x;
  if (i >= 110592) return;
  int o = i & 63;
  int c = (i >> 6) & 63;
  int t = i >> 12;
  dst[i] = src[(o * 64 + c) * 27 + t];
}

// ---------------- LayerNorm over channels (per token) ----------------
__global__ __launch_bounds__(64) void ln_kernel(const float* __restrict__ x,
                                                const float* __restrict__ g,
                                                const float* __restrict__ bb,
                                                float* __restrict__ y) {
  __shared__ float tile[64][65];
  const int blk = blockIdx.x;           // 0..127
  const int b = blk >> 6;
  const int n0 = (blk & 63) << 6;
  const int lane = threadIdx.x;
  const float* xb = x + b * 262144;
  for (int c = 0; c < 64; ++c) tile[c][lane] = xb[c * 4096 + n0 + lane];
  __syncthreads();
  float s = 0.f, s2 = 0.f;
  #pragma unroll
  for (int c = 0; c < 64; ++c) { float v = tile[c][lane]; s += v; s2 += v * v; }
  float mu = s * (1.f / 64.f);
  float var = s2 * (1.f / 64.f) - mu * mu;
  float r = rsqrtf(var + 1e-5f);
  for (int c = 0; c < 64; ++c) {
    float v = (tile[c][lane] - mu) * r * g[c] + bb[c];
    y[b * 262144 + c * 4096 + n0 + lane] = v;
  }
}

// ---------------- pointwise 64x64 conv (GEMM over 32-n tiles) ----------------
// Grid: 256 blocks (b x 128 tiles of 32 n). Thread tile: 4 o x 2 n.
// MODE 0: p1  : stage in0;                 epi: gelu(acc+bias)
// MODE 1: lk1 : stage sum of 8 partials(in0)+in1[c]; epi: acc+bias
// MODE 2: p2  : stage in0*in1;             epi: v=acc+bias+in2; out=in3+gamma[o]*v
// MODE 3: c8  : stage in0;                 epi: acc+bias+in1[idx]
template <int MODE>
__global__ __launch_bounds__(256) void pw_kernel(const float* __restrict__ in0,
                                                 const float* __restrict__ in1,
                                                 const float* __restrict__ in2,
                                                 const float* __restrict__ in3,
                                                 const float* __restrict__ wmat,
                                                 const float* __restrict__ bias,
                                                 const float* __restrict__ gamma,
                                                 float* __restrict__ out) {
  __shared__ float ins[64][32];
  __shared__ float wsm[64][68];
  const int t = threadIdx.x;
  const int b = blockIdx.x >> 7;
  const int nb = (blockIdx.x & 127) << 5;
  #pragma unroll
  for (int i = 0; i < 16; ++i) {
    int e = (i << 8) + t;
    int o = e >> 6, c = e & 63;
    wsm[o][c] = wmat[e];
  }
  #pragma unroll
  for (int i = 0; i < 8; ++i) {
    int e = (i << 8) + t;
    int c = e >> 5, j = e & 31;
    int gi = (b << 18) + (c << 12) + nb + j;
    float v;
    if (MODE == 1) {
      v = in1[c];
      #pragma unroll
      for (int s = 0; s < 8; ++s) v += in0[s * 524288 + gi];
    } else if (MODE == 2) {
      v = in0[gi] * in1[gi];
    } else {
      v = in0[gi];
    }
    ins[c][j] = v;
  }
  __syncthreads();
  const int o0 = (t >> 4) << 2, n0 = (t & 15) << 1;
  float acc[4][2];
  #pragma unroll
  for (int i = 0; i < 4; ++i) { acc[i][0] = 0.f; acc[i][1] = 0.f; }
  #pragma unroll
  for (int c4 = 0; c4 < 64; c4 += 4) {
    float2 a0 = *(const float2*)&ins[c4 + 0][n0];
    float2 a1 = *(const float2*)&ins[c4 + 1][n0];
    float2 a2v = *(const float2*)&ins[c4 + 2][n0];
    float2 a3 = *(const float2*)&ins[c4 + 3][n0];
    #pragma unroll
    for (int oi = 0; oi < 4; ++oi) {
      float4 wv = *(const float4*)&wsm[o0 + oi][c4];
      acc[oi][0] += wv.x * a0.x + wv.y * a1.x + wv.z * a2v.x + wv.w * a3.x;
      acc[oi][1] += wv.x * a0.y + wv.y * a1.y + wv.z * a2v.y + wv.w * a3.y;
    }
  }
  #pragma unroll
  for (int oi = 0; oi < 4; ++oi) {
    int o = o0 + oi;
    float bv = bias[o];
    #pragma unroll
    for (int nj = 0; nj < 2; ++nj) {
      int idx = (b << 18) + (o << 12) + nb + n0 + nj;
      float v = acc[oi][nj] + bv;
      if (MODE == 0) {
        v = 0.5f * v * (1.0f + erff(v * 0.70710678118654752f));
      } else if (MODE == 2) {
        v = v + in2[idx];
        v = in3[idx] + gamma[o] * v;
      } else if (MODE == 3) {
        v = v + in1[idx];
      }
      out[idx] = v;
    }
  }
}

// ---------------- depthwise 5x5x5, pad 2 ----------------
__global__ __launch_bounds__(256) void dw5_kernel(const float* __restrict__ in,
                                                  const float* __restrict__ w,
                                                  const float* __restrict__ bias,
                                                  float* __restrict__ out) {
  __shared__ float s[20][20][20];
  const int b = blockIdx.x >> 6, c = blockIdx.x & 63;
  const int t = threadIdx.x;
  float* sf = &s[0][0][0];
  for (int i = t; i < 8000; i += 256) sf[i] = 0.f;
  __syncthreads();
  const float* ib = in + ((b << 6) + c) * 4096;
  for (int i = t; i < 4096; i += 256) {
    int h = i >> 8, ww = (i >> 4) & 15, d = i & 15;
    s[h + 2][ww + 2][d + 2] = ib[i];
  }
  __syncthreads();
  const int h = t >> 4, ww = t & 15;
  float acc[16];
  #pragma unroll
  for (int d = 0; d < 16; ++d) acc[d] = 0.f;
  const float* wc = w + c * 125;
  #pragma unroll
  for (int kh = 0; kh < 5; ++kh) {
    #pragma unroll
    for (int kw = 0; kw < 5; ++kw) {
      const float* row = &s[h + kh][ww + kw][0];
      float r[20];
      #pragma unroll
      for (int q = 0; q < 5; ++q) {
        float4 v = *(const float4*)(row + 4 * q);
        r[4 * q] = v.x; r[4 * q + 1] = v.y; r[4 * q + 2] = v.z; r[4 * q + 3] = v.w;
      }
      #pragma unroll
      for (int kd = 0; kd < 5; ++kd) {
        float wv = wc[(kh * 5 + kw) * 5 + kd];
        #pragma unroll
        for (int d = 0; d < 16; ++d) acc[d] += wv * r[d + kd];
      }
    }
  }
  float bv = bias[c];
  const int nb = (h * 16 + ww) * 16;
  #pragma unroll
  for (int d = 0; d < 16; ++d) out[((b << 6) + c) * 4096 + nb + d] = acc[d] + bv;
}

// ---------------- depthwise 7x7x7, dilation 3, pad 9 ----------------
__global__ __launch_bounds__(256) void dw7_kernel(const float* __restrict__ in,
                                                  const float* __restrict__ w,
                                                  const float* __restrict__ bias,
                                                  float* __restrict__ out,
                                                  float* __restrict__ out_cl) {
  __shared__ float s[16][16][20];
  const int b = blockIdx.x >> 6, c = blockIdx.x & 63;
  const int t = threadIdx.x;
  const float* ib = in + ((b << 6) + c) * 4096;
  for (int i = t; i < 4096; i += 256) {
    int h = i >> 8, ww = (i >> 4) & 15, d = i & 15;
    s[h][ww][d] = ib[i];
  }
  __syncthreads();
  const int h = t >> 4, ww = t & 15;
  float acc[16];
  #pragma unroll
  for (int d = 0; d < 16; ++d) acc[d] = 0.f;
  const float* wc = w + c * 343;
  #pragma unroll
  for (int kh = 0; kh < 7; ++kh) {
    int hi = h + 3 * kh - 9;
    bool vh = (hi >= 0) && (hi < 16);
    #pragma unroll
    for (int kw = 0; kw < 7; ++kw) {
      int wi = ww + 3 * kw - 9;
      bool vv = vh && (wi >= 0) && (wi < 16);
      const float* row = vv ? &s[hi][wi][0] : &s[0][0][0];
      float m = vv ? 1.f : 0.f;
      float r[34];
      #pragma unroll
      for (int j = 0; j < 9; ++j) r[j] = 0.f;
      #pragma unroll
      for (int j = 25; j < 34; ++j) r[j] = 0.f;
      #pragma unroll
      for (int q = 0; q < 4; ++q) {
        float4 v = *(const float4*)(row + 4 * q);
        r[9 + 4 * q] = v.x; r[10 + 4 * q] = v.y; r[11 + 4 * q] = v.z; r[12 + 4 * q] = v.w;
      }
      #pragma unroll
      for (int kd = 0; kd < 7; ++kd) {
        float wv = wc[(kh * 7 + kw) * 7 + kd] * m;
        #pragma unroll
        for (int d = 0; d < 16; ++d) acc[d] += wv * r[d + 3 * kd];
      }
    }
  }
  float bv = bias[c];
  const int nb = (h * 16 + ww) * 16;
  #pragma unroll
  for (int d = 0; d < 16; ++d) {
    float v = acc[d] + bv;
    out[((b << 6) + c) * 4096 + nb + d] = v;
    out_cl[((b * 4096) + nb + d) * 64 + c] = v;
  }
}

// ---------------- dense 3x3x3 conv, pad 1, Cin=64 -> M, split-K partials -----
// Thread owns OTILE output channels x one 16-deep d-line. Input tile + halo in
// LDS (zero-filled OOB). parts[blockIdx.y][b][o][n] = partial sum over its
// CSPL input channels (no bias).
template <int M, int OTILE, int OG, int WG, int BLOCK, int CSPL>
__global__ __launch_bounds__(BLOCK) void conv3_kernel(const float* __restrict__ in,
                                                      const float* __restrict__ Wr,
                                                      float* __restrict__ parts) {
  __shared__ float sm[CSPL][3][WG + 2][20];
  const int t = threadIdx.x;
  const int WBLKS = 16 / WG;
  const int nt = blockIdx.x;                 // B*16*WBLKS blocks
  const int b = nt / (16 * WBLKS);
  const int h0 = (nt / WBLKS) % 16;
  const int wb = (nt % WBLKS) * WG;
  const int c0 = blockIdx.y * CSPL;
  const int E = CSPL * 3 * (WG + 2) * 18;
  for (int e = t; e < E; e += BLOCK) {
    int d1 = e % 18;
    int w1 = (e / 18) % (WG + 2);
    int th = (e / (18 * (WG + 2))) % 3;
    int cc = e / (54 * (WG + 2));
    int gh = h0 + th - 1, gw = wb + w1 - 1, gd = d1 - 1;
    float v = 0.f;
    if (((unsigned)gh < 16u) && ((unsigned)gw < 16u) && ((unsigned)gd < 16u))
      v = in[((b * 64 + c0 + cc) << 12) + (gh << 8) + (gw << 4) + gd];
    sm[cc][th][w1][d1] = v;
  }
  __syncthreads();
  const int og = t / WG, wg = t % WG;
  if (og < OG) {
    const int o0 = og * OTILE;
    float acc[OTILE][16];
    #pragma unroll
    for (int i = 0; i < OTILE; ++i)
      #pragma unroll
      for (int d = 0; d < 16; ++d) acc[i][d] = 0.f;
    for (int cc = 0; cc < CSPL; ++cc) {
      #pragma unroll
      for (int th = 0; th < 3; ++th) {
        #pragma unroll
        for (int tw = 0; tw < 3; ++tw) {
          const float* row = &sm[cc][th][wg + tw][0];
          float r[20];
          #pragma unroll
          for (int q = 0; q < 5; ++q) {
            float4 v = *(const float4*)(row + 4 * q);
            r[4 * q] = v.x; r[4 * q + 1] = v.y; r[4 * q + 2] = v.z; r[4 * q + 3] = v.w;
          }
          const float* wp = Wr + ((c0 + cc) * 27 + (th * 3 + tw) * 3) * M + o0;
          #pragma unroll
          for (int td = 0; td < 3; ++td) {
            float wva[OTILE];
            if (OTILE == 4) {
              float4 wq = *(const float4*)(wp + td * M);
              wva[0] = wq.x; wva[1] = wq.y; wva[2] = wq.z; wva[3] = wq.w;
            } else if (OTILE == 2) {
              float2 wq = *(const float2*)(wp + td * M);
              wva[0] = wq.x; wva[1] = wq.y;
            } else {
              #pragma unroll
              for (int i = 0; i < OTILE; ++i) wva[i] = wp[td * M + i];
            }
            #pragma unroll
            for (int d = 0; d < 16; ++d) {
              float rv = r[d + td];
              #pragma unroll
              for (int i = 0; i < OTILE; ++i) acc[i][d] += wva[i] * rv;
            }
          }
        }
      }
    }
    const int nbase = (h0 << 8) + ((wb + wg) << 4);
    #pragma unroll
    for (int i = 0; i < OTILE; ++i) {
      size_t obase = ((size_t)(blockIdx.y * 2 + b) * M + (o0 + i)) * 4096 + nbase;
      #pragma unroll
      for (int q = 0; q < 4; ++q) {
        float4 v = make_float4(acc[i][4 * q], acc[i][4 * q + 1], acc[i][4 * q + 2], acc[i][4 * q + 3]);
        *(float4*)&parts[obase + 4 * q] = v;
      }
    }
  }
}

// ---------------- offset conv partial reduce + transpose to (B,N,81) --------
__global__ __launch_bounds__(256) void offreduce_kernel(const float* __restrict__ parts,
                                                        const float* __restrict__ bias,
                                                        float* __restrict__ offcl) {
  __shared__ float ts[81][65];
  const int t = threadIdx.x;
  const int b = blockIdx.x >> 6;
  const int nb = (blockIdx.x & 63) << 6;
  for (int e = t; e < 81 * 64; e += 256) {
    int m = e >> 6, j = e & 63;
    size_t idx = ((size_t)b * 81 + m) * 4096 + nb + j;
    float v = bias[m];
    #pragma unroll
    for (int p = 0; p < 8; ++p) v += parts[(size_t)p * 663552 + idx];
    ts[m][j] = v;
  }
  __syncthreads();
  for (int e = t; e < 64 * 81; e += 256) {
    int j = e / 81, m = e % 81;
    offcl[((size_t)b * 4096 + nb + j) * 81 + m] = ts[m][j];
  }
}

// ---------------- deformable sampling + einsum (fused, per-tap GEMM) --------
// 256 threads (4 waves). Split over taps: blockIdx.y in [0,8), groups of
// 4,4,4,3,3,3,3,3 taps. GEMM thread tile: 4 o x 4 n with n rows ng+16j
// (consecutive across lanes at fixed j -> conflict-free with (nl>>3) XOR).
__global__ __launch_bounds__(256) void deform_kernel(const float* __restrict__ acl,
                                                     const float* __restrict__ offcl,
                                                     const float* __restrict__ Wd,
                                                     float* __restrict__ parts) {
  __shared__ float wsm[64][68];
  __shared__ float ssm[64][68];
  __shared__ int lin_s[64][8];
  __shared__ float wgt_s[64][8];
  const int t = threadIdx.x;
  const int b = blockIdx.x >> 6;
  const int nb = (blockIdx.x & 63) << 6;
  const int p = blockIdx.y;
  const int k0 = (p < 3) ? p * 4 : 12 + (p - 3) * 3;
  const int k1 = k0 + ((p < 3) ? 4 : 3);
  const int og = t >> 4, ng = t & 15;        // GEMM roles
  const int o0 = og << 2;
  const int snl = t >> 2, scb = (t & 3) << 4; // sampling roles: n-lane, ch-base
  const int oc0 = (t & 3) << 1;               // offset roles: corners oc0, oc0+1
  float acc[4][4];
  #pragma unroll
  for (int i = 0; i < 4; ++i)
    #pragma unroll
    for (int j = 0; j < 4; ++j) acc[i][j] = 0.f;

  for (int k = k0; k < k1; ++k) {
    __syncthreads();  // protect wsm/ssm from prior-iteration readers
    #pragma unroll
    for (int i = 0; i < 16; ++i) {
      int e = (i << 8) + t;
      wsm[e >> 6][e & 63] = Wd[(k << 12) + e];
    }
    {
      int n = nb + snl;
      int h = n >> 8, ww = (n >> 4) & 15, d = n & 15;
      const float* op = offcl + ((size_t)(b * 4096) + n) * 81 + 3 * k;
      float ph = (float)(h + (k / 9) - 1) + op[0];
      float pw = (float)(ww + ((k / 3) % 3) - 1) + op[1];
      float pd = (float)(d + (k % 3) - 1) + op[2];
      float fz = floorf(ph), fy = floorf(pw), fx = floorf(pd);
      int iz = (int)fz, iy = (int)fy, ix = (int)fx;
      float az = ph - fz, ay = pw - fy, ax = pd - fx;
      #pragma unroll
      for (int cc2 = 0; cc2 < 2; ++cc2) {
        int cor = oc0 + cc2;
        int dz = cor >> 2, dy = (cor >> 1) & 1, dx = cor & 1;
        int zi = iz + dz, yi = iy + dy, xi = ix + dx;
        float wz = dz ? az : 1.f - az;
        float wy = dy ? ay : 1.f - ay;
        float wx = dx ? ax : 1.f - ax;
        bool valid = ((unsigned)zi < 16u) && ((unsigned)yi < 16u) && ((unsigned)xi < 16u);
        int zc = min(max(zi, 0), 15), yc = min(max(yi, 0), 15), xc = min(max(xi, 0), 15);
        lin_s[snl][cor] = (zc << 8) + (yc << 4) + xc;
        wgt_s[snl][cor] = valid ? wz * wy * wx : 0.f;
      }
    }
    __syncthreads();
    {
      float sv[16];
      #pragma unroll
      for (int q = 0; q < 16; ++q) sv[q] = 0.f;
      const float* abase = acl + (size_t)(b * 4096) * 64;
      #pragma unroll
      for (int cor = 0; cor < 8; ++cor) {
        int lin = lin_s[snl][cor];
        float wg = wgt_s[snl][cor];
        const float* src = abase + lin * 64 + scb;
        #pragma unroll
        for (int q = 0; q < 4; ++q) {
          float4 v = *(const float4*)(src + 4 * q);
          sv[4 * q + 0] += wg * v.x; sv[4 * q + 1] += wg * v.y;
          sv[4 * q + 2] += wg * v.z; sv[4 * q + 3] += wg * v.w;
        }
      }
      int sw = ((snl >> 3) & 7) << 2;
      #pragma unroll
      for (int q = 0; q < 4; ++q) {
        int cidx = (scb + 4 * q) ^ sw;
        *(float4*)&ssm[snl][cidx] = make_float4(sv[4 * q], sv[4 * q + 1], sv[4 * q + 2], sv[4 * q + 3]);
      }
    }
    __syncthreads();
    #pragma unroll
    for (int c4 = 0; c4 < 64; c4 += 4) {
      float sva[4][4];
      #pragma unroll
      for (int j = 0; j < 4; ++j) {
        int nl = ng + (j << 4);
        int cidx = c4 ^ (((nl >> 3) & 7) << 2);
        float4 v = *(const float4*)&ssm[nl][cidx];
        sva[j][0] = v.x; sva[j][1] = v.y; sva[j][2] = v.z; sva[j][3] = v.w;
      }
      #pragma unroll
      for (int cj = 0; cj < 4; ++cj) {
        float4 wv = *(const float4*)&wsm[c4 + cj][o0];
        #pragma unroll
        for (int j = 0; j < 4; ++j) {
          float scl = sva[j][cj];
          acc[0][j] += wv.x * scl;
          acc[1][j] += wv.y * scl;
          acc[2][j] += wv.z * scl;
          acc[3][j] += wv.w * scl;
        }
      }
    }
  }
  #pragma unroll
  for (int i = 0; i < 4; ++i) {
    size_t base = ((size_t)(blockIdx.y * 2 + b) * 64 + (o0 + i)) * 4096 + nb + ng;
    parts[base]      = acc[i][0];
    parts[base + 16] = acc[i][1];
    parts[base + 32] = acc[i][2];
    parts[base + 48] = acc[i][3];
  }
}

// ---------------- BN stats: reduce 8 split-K partials + per-channel sums ----
__global__ __launch_bounds__(256) void stats_kernel(const float* __restrict__ parts,
                                                    const float* __restrict__ bias,
                                                    float* __restrict__ rsum,
                                                    float2* __restrict__ statp) {
  const int c = blockIdx.x, slab = blockIdx.y;
  const int t = threadIdx.x;
  float bv = bias[c];
  float s1 = 0.f, s2 = 0.f;
  #pragma unroll
  for (int i = 0; i < 4; ++i) {
    int idx = (slab << 10) + (i << 8) + t;
    int b = idx >> 12, n = idx & 4095;
    size_t gi = ((size_t)(b * 64 + c) << 12) + n;
    float v = bv;
    #pragma unroll
    for (int p = 0; p < 8; ++p) v += parts[((size_t)p << 19) + gi];
    rsum[gi] = v;
    s1 += v; s2 += v * v;
  }
  __shared__ float red[8];
  for (int o = 32; o > 0; o >>= 1) { s1 += __shfl_down(s1, o); s2 += __shfl_down(s2, o); }
  int wid = t >> 6;
  if ((t & 63) == 0) { red[wid * 2] = s1; red[wid * 2 + 1] = s2; }
  __syncthreads();
  if (t == 0) {
    float a = 0.f, b2 = 0.f;
    #pragma unroll
    for (int wv = 0; wv < 4; ++wv) { a += red[wv * 2]; b2 += red[wv * 2 + 1]; }
    statp[c * 8 + slab] = make_float2(a, b2);
  }
}

__global__ void combine_kernel(const float2* __restrict__ statp,
                               const float* __restrict__ g,
                               const float* __restrict__ bb,
                               float2* __restrict__ bnp) {
  int c = threadIdx.x;
  if (c < 64) {
    float s1 = 0.f, s2 = 0.f;
    #pragma unroll
    for (int s = 0; s < 8; ++s) { float2 v = statp[c * 8 + s]; s1 += v.x; s2 += v.y; }
    float mu = s1 * (1.f / 8192.f);
    float var = s2 * (1.f / 8192.f) - mu * mu;
    float scale = g[c] * rsqrtf(var + 1e-5f);
    bnp[c] = make_float2(scale, bb[c] - mu * scale);
  }
}

// ---------------- BN apply (+optional skip) + leaky relu --------------------
template <int WITHSKIP>
__global__ __launch_bounds__(256) void bnapply_kernel(const float* __restrict__ rsum,
                                                      const float2* __restrict__ bnp,
                                                      const float* __restrict__ skip,
                                                      float* __restrict__ out) {
  int e = (blockIdx.x * 256 + threadIdx.x) << 2;
  int c = (e >> 12) & 63;
  float2 p = bnp[c];
  float4 v = *(const float4*)&rsum[e];
  float4 s = make_float4(0.f, 0.f, 0.f, 0.f);
  if (WITHSKIP) s = *(const float4*)&skip[e];
  float4 r;
  float u;
  u = v.x * p.x + p.y + s.x; r.x = u > 0.f ? u : 0.01f * u;
  u = v.y * p.x + p.y + s.y; r.y = u > 0.f ? u : 0.01f * u;
  u = v.z * p.x + p.y + s.z; r.z = u > 0.f ? u : 0.01f * u;
  u = v.w * p.x + p.y + s.w; r.w = u > 0.f ? u : 0.01f * u;
  *(float4*)&out[e] = r;
}

// ---------------------------------------------------------------------------
extern "C" void kernel_launch(void* const* d_in, const int* in_sizes, int n_in,
                              void* d_out, int out_size, void* d_ws, size_t ws_size,
                              hipStream_t stream) {
  (void)in_sizes; (void)n_in; (void)out_size; (void)ws_size;
  const float* x     = (const float*)d_in[0];
  const float* ln_g  = (const float*)d_in[1];
  const float* ln_b  = (const float*)d_in[2];
  const float* gamma = (const float*)d_in[3];
  const float* p1_w  = (const float*)d_in[4];
  const float* p1_b  = (const float*)d_in[5];
  const float* c0_w  = (const float*)d_in[6];
  const float* c0_b  = (const float*)d_in[7];
  const float* cs_w  = (const float*)d_in[8];
  const float* cs_b  = (const float*)d_in[9];
  const float* off_w = (const float*)d_in[10];
  const float* off_b = (const float*)d_in[11];
  const float* def_w = (const float*)d_in[12];
  const float* def_b = (const float*)d_in[13];
  const float* lk1_w = (const float*)d_in[14];
  const float* lk1_b = (const float*)d_in[15];
  const float* p2_w  = (const float*)d_in[16];
  const float* p2_b  = (const float*)d_in[17];
  const float* r1_w  = (const float*)d_in[18];
  const float* r1_b  = (const float*)d_in[19];
  const float* bn1_g = (const float*)d_in[20];
  const float* bn1_b = (const float*)d_in[21];
  const float* r2_w  = (const float*)d_in[22];
  const float* r2_b  = (const float*)d_in[23];
  const float* bn2_g = (const float*)d_in[24];
  const float* bn2_b = (const float*)d_in[25];
  const float* c8_w  = (const float*)d_in[26];
  const float* c8_b  = (const float*)d_in[27];
  float* outp = (float*)d_out;

  float* wsp = (float*)d_ws;
  size_t ofs = 0;
  auto alloc = [&](size_t n) { float* p = wsp + ofs; ofs += n; return p; };
  // NOTE: offparts must be immediately followed by parts8: the 8 offset-conv
  // slabs (5,308,416 floats) overflow into parts8's head, which is dead then.
  float* ybuf     = alloc(524288);   // LN out (shortcut); later reused as o1
  float* ubuf     = alloc(524288);   // gelu(p1); later reused as o3
  float* abuf     = alloc(524288);   // dw5 out
  float* a2       = alloc(524288);   // dw7 out (channel-major)
  float* a2cl     = alloc(524288);   // dw7 out (channel-last)
  float* offparts = alloc(2654208);  // offset-conv partials slabs 0-3
  float* parts8   = alloc(4194304);  // slabs 4-7 overflow; deform partials; r1/r2 partials
  float* offcl    = alloc(663552);   // offsets (B,N,81)
  float* l1       = alloc(524288);   // lk1 out
  float* skipb    = alloc(524288);   // skip (B,C,N)
  float* rsum     = alloc(524288);   // reduced conv out
  float2* statp   = (float2*)alloc(1024);
  float2* bnp     = (float2*)alloc(128);
  float* wr1      = alloc(110592);
  float* wr2      = alloc(110592);
  float* wroff    = alloc(139968);
  float* wdd      = alloc(110592);
  float* dparts = parts8;            // deform partials (8 x 524288, exact fit)
  float* o1 = ybuf;
  float* o3 = ubuf;

  // weight repacks
  repackA_kernel<<<(110592 + 255) / 256, 256, 0, stream>>>(r1_w, wr1, 64, 110592);
  repackA_kernel<<<(110592 + 255) / 256, 256, 0, stream>>>(r2_w, wr2, 64, 110592);
  repackA_kernel<<<(139968 + 255) / 256, 256, 0, stream>>>(off_w, wroff, 81, 139968);
  repackB_kernel<<<(110592 + 255) / 256, 256, 0, stream>>>(def_w, wdd);

  // 1. LayerNorm
  ln_kernel<<<128, 64, 0, stream>>>(x, ln_g, ln_b, ybuf);
  // 2. p1 1x1 + gelu (256 blocks, 32-n tiles)
  pw_kernel<0><<<256, 256, 0, stream>>>(ybuf, nullptr, nullptr, nullptr, p1_w, p1_b, nullptr, ubuf);
  // 3. depthwise 5^3
  dw5_kernel<<<128, 256, 0, stream>>>(ubuf, c0_w, c0_b, abuf);
  // 4. depthwise 7^3 dil3
  dw7_kernel<<<128, 256, 0, stream>>>(abuf, cs_w, cs_b, a2, a2cl);
  // 5. offset conv (64->81, 3^3) split-K 8, 256-thread blocks (WG=8)
  conv3_kernel<81, 3, 27, 8, 256, 8><<<dim3(64, 8), 256, 0, stream>>>(a2, wroff, offparts);
  offreduce_kernel<<<128, 256, 0, stream>>>(offparts, off_b, offcl);
  // 6. deformable sampling + einsum, 256-thread blocks, 8 tap-groups
  deform_kernel<<<dim3(128, 8), 256, 0, stream>>>(a2cl, offcl, wdd, dparts);
  // 7. lk1 1x1 (stages sum of 8 deform partials + def_b)
  pw_kernel<1><<<256, 256, 0, stream>>>(dparts, def_b, nullptr, nullptr, lk1_w, lk1_b, nullptr, l1);
  // 8. p2 1x1 on u*l1, +shortcut, then skip = x + gamma*y9
  pw_kernel<2><<<256, 256, 0, stream>>>(ubuf, l1, ybuf, x, p2_w, p2_b, gamma, skipb);
  // 9. r1 3^3 conv split-K 8 (256-thread, OTILE=1) -> BN1 -> lrelu
  conv3_kernel<64, 1, 64, 4, 256, 8><<<dim3(128, 8), 256, 0, stream>>>(skipb, wr1, parts8);
  stats_kernel<<<dim3(64, 8), 256, 0, stream>>>(parts8, r1_b, rsum, statp);
  combine_kernel<<<1, 64, 0, stream>>>(statp, bn1_g, bn1_b, bnp);
  bnapply_kernel<0><<<512, 256, 0, stream>>>(rsum, bnp, nullptr, o1);
  // 10. r2 3^3 conv split-K 8 (256-thread, OTILE=1) -> BN2 -> (+skip) -> lrelu
  conv3_kernel<64, 1, 64, 4, 256, 8><<<dim3(128, 8), 256, 0, stream>>>(o1, wr2, parts8);
  stats_kernel<<<dim3(64, 8), 256, 0, stream>>>(parts8, r2_b, rsum, statp);
  combine_kernel<<<1, 64, 0, stream>>>(statp, bn2_g, bn2_b, bnp);
  bnapply_kernel<1><<<512, 256, 0, stream>>>(rsum, bnp, skipb, o3);
  // 11. final: out = skip + c8(o3)
  pw_kernel<3><<<256, 256, 0, stream>>>(o3, skipb, nullptr, nullptr, c8_w, c8_b, nullptr, outp);
}

// Round 10
// 392.700 us; speedup vs baseline: 1.2091x; 1.2091x over previous
//
#include <hip/hip_runtime.h>
#include <math.h>

// ---------------------------------------------------------------------------
// Problem constants: B=2, C=64, H=W=D=16, N=4096 positions per batch.
// All tensors fp32. Channel-major layout (B,C,N) unless noted "_cl" (B,N,C).
// ---------------------------------------------------------------------------

// ---------------- weight repack kernels ----------------
// repackA: dst[c][t][o] = src[o][c][t]   (for direct 3x3x3 convs)
__global__ __launch_bounds__(256) void repackA_kernel(const float* __restrict__ src,
                                                      float* __restrict__ dst,
                                                      int M, int total) {
  int i = blockIdx.x * 256 + threadIdx.x;
  if (i >= total) return;
  int o = i % M;
  int t = (i / M) % 27;
  int c = i / (27 * M);
  dst[i] = src[(o * 64 + c) * 27 + t];
}

// repackB: dst[t][c][o] = src[o][c][t]   (for deform einsum, M=64)
__global__ __launch_bounds__(256) void repackB_kernel(const float* __restrict__ src,
                                                      float* __restrict__ dst) {
  int i = blockIdx.x * 256 + threadIdx.x;
  if (i >= 110592) return;
  int o = i & 63;
  int c = (i >> 6) & 63;
  int t = i >> 12;
  dst[i] = src[(o * 64 + c) * 27 + t];
}

// ---------------- LayerNorm over channels (per token) ----------------
__global__ __launch_bounds__(64) void ln_kernel(const float* __restrict__ x,
                                                const float* __restrict__ g,
                                                const float* __restrict__ bb,
                                                float* __restrict__ y) {
  __shared__ float tile[64][65];
  const int blk = blockIdx.x;           // 0..127
  const int b = blk >> 6;
  const int n0 = (blk & 63) << 6;
  const int lane = threadIdx.x;
  const float* xb = x + b * 262144;
  for (int c = 0; c < 64; ++c) tile[c][lane] = xb[c * 4096 + n0 + lane];
  __syncthreads();
  float s = 0.f, s2 = 0.f;
  #pragma unroll
  for (int c = 0; c < 64; ++c) { float v = tile[c][lane]; s += v; s2 += v * v; }
  float mu = s * (1.f / 64.f);
  float var = s2 * (1.f / 64.f) - mu * mu;
  float r = rsqrtf(var + 1e-5f);
  for (int c = 0; c < 64; ++c) {
    float v = (tile[c][lane] - mu) * r * g[c] + bb[c];
    y[b * 262144 + c * 4096 + n0 + lane] = v;
  }
}

// ---------------- pointwise 64x64 conv (GEMM over 64-n tiles) ----------------
// MODE 0: p1  : stage in0;                 epi: gelu(acc+bias)
// MODE 1: lk1 : stage sum of 8 partials(in0)+in1[c]; epi: acc+bias
// MODE 2: p2  : stage in0*in1;             epi: v=acc+bias+in2; out=in3+gamma[o]*v
// MODE 3: c8  : stage in0;                 epi: acc+bias+in1[idx]
template <int MODE>
__global__ __launch_bounds__(256) void pw_kernel(const float* __restrict__ in0,
                                                 const float* __restrict__ in1,
                                                 const float* __restrict__ in2,
                                                 const float* __restrict__ in3,
                                                 const float* __restrict__ wmat,
                                                 const float* __restrict__ bias,
                                                 const float* __restrict__ gamma,
                                                 float* __restrict__ out) {
  __shared__ float ins[64][64];
  __shared__ float wsm[64][68];
  const int t = threadIdx.x;
  const int b = blockIdx.x >> 6;
  const int nb = (blockIdx.x & 63) << 6;
  #pragma unroll
  for (int i = 0; i < 16; ++i) {
    int e = (i << 8) + t;
    int o = e >> 6, c = e & 63;
    wsm[o][c] = wmat[e];
  }
  #pragma unroll
  for (int i = 0; i < 16; ++i) {
    int e = (i << 8) + t;
    int c = e >> 6, j = e & 63;
    int gi = (b << 18) + (c << 12) + nb + j;
    float v;
    if (MODE == 1) {
      v = in1[c];
      #pragma unroll
      for (int s = 0; s < 8; ++s) v += in0[s * 524288 + gi];
    } else if (MODE == 2) {
      v = in0[gi] * in1[gi];
    } else {
      v = in0[gi];
    }
    ins[c][j] = v;
  }
  __syncthreads();
  const int o0 = (t >> 4) << 2, n0 = (t & 15) << 2;
  float acc[4][4];
  #pragma unroll
  for (int i = 0; i < 4; ++i)
    #pragma unroll
    for (int j = 0; j < 4; ++j) acc[i][j] = 0.f;
  #pragma unroll
  for (int c4 = 0; c4 < 64; c4 += 4) {
    float4 a0 = *(const float4*)&ins[c4 + 0][n0];
    float4 a1 = *(const float4*)&ins[c4 + 1][n0];
    float4 a2v = *(const float4*)&ins[c4 + 2][n0];
    float4 a3 = *(const float4*)&ins[c4 + 3][n0];
    #pragma unroll
    for (int oi = 0; oi < 4; ++oi) {
      float4 wv = *(const float4*)&wsm[o0 + oi][c4];
      acc[oi][0] += wv.x * a0.x + wv.y * a1.x + wv.z * a2v.x + wv.w * a3.x;
      acc[oi][1] += wv.x * a0.y + wv.y * a1.y + wv.z * a2v.y + wv.w * a3.y;
      acc[oi][2] += wv.x * a0.z + wv.y * a1.z + wv.z * a2v.z + wv.w * a3.z;
      acc[oi][3] += wv.x * a0.w + wv.y * a1.w + wv.z * a2v.w + wv.w * a3.w;
    }
  }
  #pragma unroll
  for (int oi = 0; oi < 4; ++oi) {
    int o = o0 + oi;
    float bv = bias[o];
    #pragma unroll
    for (int nj = 0; nj < 4; ++nj) {
      int idx = (b << 18) + (o << 12) + nb + n0 + nj;
      float v = acc[oi][nj] + bv;
      if (MODE == 0) {
        v = 0.5f * v * (1.0f + erff(v * 0.70710678118654752f));
      } else if (MODE == 2) {
        v = v + in2[idx];
        v = in3[idx] + gamma[o] * v;
      } else if (MODE == 3) {
        v = v + in1[idx];
      }
      out[idx] = v;
    }
  }
}

// ---------------- depthwise 5x5x5, pad 2 ----------------
__global__ __launch_bounds__(256) void dw5_kernel(const float* __restrict__ in,
                                                  const float* __restrict__ w,
                                                  const float* __restrict__ bias,
                                                  float* __restrict__ out) {
  __shared__ float s[20][20][20];
  const int b = blockIdx.x >> 6, c = blockIdx.x & 63;
  const int t = threadIdx.x;
  float* sf = &s[0][0][0];
  for (int i = t; i < 8000; i += 256) sf[i] = 0.f;
  __syncthreads();
  const float* ib = in + ((b << 6) + c) * 4096;
  for (int i = t; i < 4096; i += 256) {
    int h = i >> 8, ww = (i >> 4) & 15, d = i & 15;
    s[h + 2][ww + 2][d + 2] = ib[i];
  }
  __syncthreads();
  const int h = t >> 4, ww = t & 15;
  float acc[16];
  #pragma unroll
  for (int d = 0; d < 16; ++d) acc[d] = 0.f;
  const float* wc = w + c * 125;
  #pragma unroll
  for (int kh = 0; kh < 5; ++kh) {
    #pragma unroll
    for (int kw = 0; kw < 5; ++kw) {
      const float* row = &s[h + kh][ww + kw][0];
      float r[20];
      #pragma unroll
      for (int q = 0; q < 5; ++q) {
        float4 v = *(const float4*)(row + 4 * q);
        r[4 * q] = v.x; r[4 * q + 1] = v.y; r[4 * q + 2] = v.z; r[4 * q + 3] = v.w;
      }
      #pragma unroll
      for (int kd = 0; kd < 5; ++kd) {
        float wv = wc[(kh * 5 + kw) * 5 + kd];
        #pragma unroll
        for (int d = 0; d < 16; ++d) acc[d] += wv * r[d + kd];
      }
    }
  }
  float bv = bias[c];
  const int nb = (h * 16 + ww) * 16;
  #pragma unroll
  for (int d = 0; d < 16; ++d) out[((b << 6) + c) * 4096 + nb + d] = acc[d] + bv;
}

// ---------------- depthwise 7x7x7, dilation 3, pad 9 (channel-major out only)
__global__ __launch_bounds__(256) void dw7_kernel(const float* __restrict__ in,
                                                  const float* __restrict__ w,
                                                  const float* __restrict__ bias,
                                                  float* __restrict__ out) {
  __shared__ float s[16][16][20];
  const int b = blockIdx.x >> 6, c = blockIdx.x & 63;
  const int t = threadIdx.x;
  const float* ib = in + ((b << 6) + c) * 4096;
  for (int i = t; i < 4096; i += 256) {
    int h = i >> 8, ww = (i >> 4) & 15, d = i & 15;
    s[h][ww][d] = ib[i];
  }
  __syncthreads();
  const int h = t >> 4, ww = t & 15;
  float acc[16];
  #pragma unroll
  for (int d = 0; d < 16; ++d) acc[d] = 0.f;
  const float* wc = w + c * 343;
  #pragma unroll
  for (int kh = 0; kh < 7; ++kh) {
    int hi = h + 3 * kh - 9;
    bool vh = (hi >= 0) && (hi < 16);
    #pragma unroll
    for (int kw = 0; kw < 7; ++kw) {
      int wi = ww + 3 * kw - 9;
      bool vv = vh && (wi >= 0) && (wi < 16);
      const float* row = vv ? &s[hi][wi][0] : &s[0][0][0];
      float m = vv ? 1.f : 0.f;
      float r[34];
      #pragma unroll
      for (int j = 0; j < 9; ++j) r[j] = 0.f;
      #pragma unroll
      for (int j = 25; j < 34; ++j) r[j] = 0.f;
      #pragma unroll
      for (int q = 0; q < 4; ++q) {
        float4 v = *(const float4*)(row + 4 * q);
        r[9 + 4 * q] = v.x; r[10 + 4 * q] = v.y; r[11 + 4 * q] = v.z; r[12 + 4 * q] = v.w;
      }
      #pragma unroll
      for (int kd = 0; kd < 7; ++kd) {
        float wv = wc[(kh * 7 + kw) * 7 + kd] * m;
        #pragma unroll
        for (int d = 0; d < 16; ++d) acc[d] += wv * r[d + 3 * kd];
      }
    }
  }
  float bv = bias[c];
  const int nb = (h * 16 + ww) * 16;
  #pragma unroll
  for (int d = 0; d < 16; ++d) out[((b << 6) + c) * 4096 + nb + d] = acc[d] + bv;
}

// ---------------- (B,C,N) -> (B,N,C) transpose via LDS 64x64 tile ----------
__global__ __launch_bounds__(256) void transpose_kernel(const float* __restrict__ in,
                                                        float* __restrict__ out) {
  __shared__ float tile[64][65];
  const int b = blockIdx.x >> 6;
  const int n0 = (blockIdx.x & 63) << 6;
  const int t = threadIdx.x;
  #pragma unroll
  for (int i = 0; i < 16; ++i) {
    int e = (i << 8) + t;
    int c = e >> 6, j = e & 63;
    tile[c][j] = in[(b << 18) + (c << 12) + n0 + j];
  }
  __syncthreads();
  #pragma unroll
  for (int i = 0; i < 16; ++i) {
    int e = (i << 8) + t;
    int j = e >> 6, c = e & 63;
    out[((size_t)((b << 12) + n0 + j)) * 64 + c] = tile[c][j];
  }
}

// ---------------- dense 3x3x3 conv, pad 1, Cin=64 -> M, split-K partials -----
// Thread owns OTILE output channels x one 16-deep d-line. Input tile + halo in
// LDS (zero-filled OOB). parts[blockIdx.y][b][o][n] = partial sum over its
// CSPL input channels (no bias).
template <int M, int OTILE, int OG, int WG, int BLOCK, int CSPL>
__global__ __launch_bounds__(BLOCK) void conv3_kernel(const float* __restrict__ in,
                                                      const float* __restrict__ Wr,
                                                      float* __restrict__ parts) {
  __shared__ float sm[CSPL][3][WG + 2][20];
  const int t = threadIdx.x;
  const int WBLKS = 16 / WG;
  const int nt = blockIdx.x;                 // B*16*WBLKS blocks
  const int b = nt / (16 * WBLKS);
  const int h0 = (nt / WBLKS) % 16;
  const int wb = (nt % WBLKS) * WG;
  const int c0 = blockIdx.y * CSPL;
  const int E = CSPL * 3 * (WG + 2) * 18;
  for (int e = t; e < E; e += BLOCK) {
    int d1 = e % 18;
    int w1 = (e / 18) % (WG + 2);
    int th = (e / (18 * (WG + 2))) % 3;
    int cc = e / (54 * (WG + 2));
    int gh = h0 + th - 1, gw = wb + w1 - 1, gd = d1 - 1;
    float v = 0.f;
    if (((unsigned)gh < 16u) && ((unsigned)gw < 16u) && ((unsigned)gd < 16u))
      v = in[((b * 64 + c0 + cc) << 12) + (gh << 8) + (gw << 4) + gd];
    sm[cc][th][w1][d1] = v;
  }
  __syncthreads();
  const int og = t / WG, wg = t % WG;
  if (og < OG) {
    const int o0 = og * OTILE;
    float acc[OTILE][16];
    #pragma unroll
    for (int i = 0; i < OTILE; ++i)
      #pragma unroll
      for (int d = 0; d < 16; ++d) acc[i][d] = 0.f;
    for (int cc = 0; cc < CSPL; ++cc) {
      #pragma unroll
      for (int th = 0; th < 3; ++th) {
        #pragma unroll
        for (int tw = 0; tw < 3; ++tw) {
          const float* row = &sm[cc][th][wg + tw][0];
          float r[20];
          #pragma unroll
          for (int q = 0; q < 5; ++q) {
            float4 v = *(const float4*)(row + 4 * q);
            r[4 * q] = v.x; r[4 * q + 1] = v.y; r[4 * q + 2] = v.z; r[4 * q + 3] = v.w;
          }
          const float* wp = Wr + ((c0 + cc) * 27 + (th * 3 + tw) * 3) * M + o0;
          #pragma unroll
          for (int td = 0; td < 3; ++td) {
            float wva[OTILE];
            if (OTILE == 4) {
              float4 wq = *(const float4*)(wp + td * M);
              wva[0] = wq.x; wva[1] = wq.y; wva[2] = wq.z; wva[3] = wq.w;
            } else if (OTILE == 2) {
              float2 wq = *(const float2*)(wp + td * M);
              wva[0] = wq.x; wva[1] = wq.y;
            } else {
              #pragma unroll
              for (int i = 0; i < OTILE; ++i) wva[i] = wp[td * M + i];
            }
            #pragma unroll
            for (int d = 0; d < 16; ++d) {
              float rv = r[d + td];
              #pragma unroll
              for (int i = 0; i < OTILE; ++i) acc[i][d] += wva[i] * rv;
            }
          }
        }
      }
    }
    const int nbase = (h0 << 8) + ((wb + wg) << 4);
    #pragma unroll
    for (int i = 0; i < OTILE; ++i) {
      size_t obase = ((size_t)(blockIdx.y * 2 + b) * M + (o0 + i)) * 4096 + nbase;
      #pragma unroll
      for (int q = 0; q < 4; ++q) {
        float4 v = make_float4(acc[i][4 * q], acc[i][4 * q + 1], acc[i][4 * q + 2], acc[i][4 * q + 3]);
        *(float4*)&parts[obase + 4 * q] = v;
      }
    }
  }
}

// ---------------- offset conv partial reduce + transpose to (B,N,81) --------
__global__ __launch_bounds__(256) void offreduce_kernel(const float* __restrict__ parts,
                                                        const float* __restrict__ bias,
                                                        float* __restrict__ offcl) {
  __shared__ float ts[81][65];
  const int t = threadIdx.x;
  const int b = blockIdx.x >> 6;
  const int nb = (blockIdx.x & 63) << 6;
  for (int e = t; e < 81 * 64; e += 256) {
    int m = e >> 6, j = e & 63;
    size_t idx = ((size_t)b * 81 + m) * 4096 + nb + j;
    float v = bias[m];
    #pragma unroll
    for (int p = 0; p < 8; ++p) v += parts[(size_t)p * 663552 + idx];
    ts[m][j] = v;
  }
  __syncthreads();
  for (int e = t; e < 64 * 81; e += 256) {
    int j = e / 81, m = e % 81;
    offcl[((size_t)b * 4096 + nb + j) * 81 + m] = ts[m][j];
  }
}

// ---------------- deformable sampling + einsum (fused, per-tap GEMM) --------
// 256 threads (4 waves). Split over taps: blockIdx.y in [0,8), groups of
// 4,4,4,3,3,3,3,3 taps. Per tap: [wsm load + offsets] | [sampling->ssm] | GEMM.
// GEMM thread tile: 4 o x 4 n (og=t>>4, ng=t&15). Sampling: 16 ch/thread.
__global__ __launch_bounds__(256) void deform_kernel(const float* __restrict__ acl,
                                                     const float* __restrict__ offcl,
                                                     const float* __restrict__ Wd,
                                                     float* __restrict__ parts) {
  __shared__ float wsm[64][68];
  __shared__ float ssm[64][68];
  __shared__ int lin_s[64][8];
  __shared__ float wgt_s[64][8];
  const int t = threadIdx.x;
  const int b = blockIdx.x >> 6;
  const int nb = (blockIdx.x & 63) << 6;
  const int p = blockIdx.y;
  const int k0 = (p < 3) ? p * 4 : 12 + (p - 3) * 3;
  const int k1 = k0 + ((p < 3) ? 4 : 3);
  const int og = t >> 4, ng = t & 15;        // GEMM roles
  const int o0 = og << 2;
  const int snl = t >> 2, scb = (t & 3) << 4; // sampling roles: n-lane, ch-base
  const int oc0 = (t & 3) << 1;               // offset roles: corners oc0, oc0+1
  float acc[4][4];
  #pragma unroll
  for (int i = 0; i < 4; ++i)
    #pragma unroll
    for (int j = 0; j < 4; ++j) acc[i][j] = 0.f;

  for (int k = k0; k < k1; ++k) {
    __syncthreads();  // protect wsm/ssm from prior-iteration readers
    #pragma unroll
    for (int i = 0; i < 16; ++i) {
      int e = (i << 8) + t;
      wsm[e >> 6][e & 63] = Wd[(k << 12) + e];
    }
    {
      int n = nb + snl;
      int h = n >> 8, ww = (n >> 4) & 15, d = n & 15;
      const float* op = offcl + ((size_t)(b * 4096) + n) * 81 + 3 * k;
      float ph = (float)(h + (k / 9) - 1) + op[0];
      float pw = (float)(ww + ((k / 3) % 3) - 1) + op[1];
      float pd = (float)(d + (k % 3) - 1) + op[2];
      float fz = floorf(ph), fy = floorf(pw), fx = floorf(pd);
      int iz = (int)fz, iy = (int)fy, ix = (int)fx;
      float az = ph - fz, ay = pw - fy, ax = pd - fx;
      #pragma unroll
      for (int cc2 = 0; cc2 < 2; ++cc2) {
        int cor = oc0 + cc2;
        int dz = cor >> 2, dy = (cor >> 1) & 1, dx = cor & 1;
        int zi = iz + dz, yi = iy + dy, xi = ix + dx;
        float wz = dz ? az : 1.f - az;
        float wy = dy ? ay : 1.f - ay;
        float wx = dx ? ax : 1.f - ax;
        bool valid = ((unsigned)zi < 16u) && ((unsigned)yi < 16u) && ((unsigned)xi < 16u);
        int zc = min(max(zi, 0), 15), yc = min(max(yi, 0), 15), xc = min(max(xi, 0), 15);
        lin_s[snl][cor] = (zc << 8) + (yc << 4) + xc;
        wgt_s[snl][cor] = valid ? wz * wy * wx : 0.f;
      }
    }
    __syncthreads();
    {
      float sv[16];
      #pragma unroll
      for (int q = 0; q < 16; ++q) sv[q] = 0.f;
      const float* abase = acl + (size_t)(b * 4096) * 64;
      #pragma unroll
      for (int cor = 0; cor < 8; ++cor) {
        int lin = lin_s[snl][cor];
        float wg = wgt_s[snl][cor];
        const float* src = abase + lin * 64 + scb;
        #pragma unroll
        for (int q = 0; q < 4; ++q) {
          float4 v = *(const float4*)(src + 4 * q);
          sv[4 * q + 0] += wg * v.x; sv[4 * q + 1] += wg * v.y;
          sv[4 * q + 2] += wg * v.z; sv[4 * q + 3] += wg * v.w;
        }
      }
      int sw = ((snl >> 3) & 7) << 2;
      #pragma unroll
      for (int q = 0; q < 4; ++q) {
        int cidx = (scb + 4 * q) ^ sw;
        *(float4*)&ssm[snl][cidx] = make_float4(sv[4 * q], sv[4 * q + 1], sv[4 * q + 2], sv[4 * q + 3]);
      }
    }
    __syncthreads();
    #pragma unroll
    for (int c4 = 0; c4 < 64; c4 += 4) {
      float sva[4][4];
      #pragma unroll
      for (int j = 0; j < 4; ++j) {
        int nl = (ng << 2) + j;
        int cidx = c4 ^ (((nl >> 3) & 7) << 2);
        float4 v = *(const float4*)&ssm[nl][cidx];
        sva[j][0] = v.x; sva[j][1] = v.y; sva[j][2] = v.z; sva[j][3] = v.w;
      }
      #pragma unroll
      for (int cj = 0; cj < 4; ++cj) {
        float4 wv = *(const float4*)&wsm[c4 + cj][o0];
        #pragma unroll
        for (int j = 0; j < 4; ++j) {
          float scl = sva[j][cj];
          acc[0][j] += wv.x * scl;
          acc[1][j] += wv.y * scl;
          acc[2][j] += wv.z * scl;
          acc[3][j] += wv.w * scl;
        }
      }
    }
  }
  #pragma unroll
  for (int i = 0; i < 4; ++i) {
    size_t base = ((size_t)(blockIdx.y * 2 + b) * 64 + (o0 + i)) * 4096 + nb + (ng << 2);
    *(float4*)&parts[base] = make_float4(acc[i][0], acc[i][1], acc[i][2], acc[i][3]);
  }
}

// ---------------- BN stats: reduce 8 split-K partials + per-channel sums ----
__global__ __launch_bounds__(256) void stats_kernel(const float* __restrict__ parts,
                                                    const float* __restrict__ bias,
                                                    float* __restrict__ rsum,
                                                    float2* __restrict__ statp) {
  const int c = blockIdx.x, slab = blockIdx.y;
  const int t = threadIdx.x;
  float bv = bias[c];
  float s1 = 0.f, s2 = 0.f;
  #pragma unroll
  for (int i = 0; i < 4; ++i) {
    int idx = (slab << 10) + (i << 8) + t;
    int b = idx >> 12, n = idx & 4095;
    size_t gi = ((size_t)(b * 64 + c) << 12) + n;
    float v = bv;
    #pragma unroll
    for (int p = 0; p < 8; ++p) v += parts[((size_t)p << 19) + gi];
    rsum[gi] = v;
    s1 += v; s2 += v * v;
  }
  __shared__ float red[8];
  for (int o = 32; o > 0; o >>= 1) { s1 += __shfl_down(s1, o); s2 += __shfl_down(s2, o); }
  int wid = t >> 6;
  if ((t & 63) == 0) { red[wid * 2] = s1; red[wid * 2 + 1] = s2; }
  __syncthreads();
  if (t == 0) {
    float a = 0.f, b2 = 0.f;
    #pragma unroll
    for (int wv = 0; wv < 4; ++wv) { a += red[wv * 2]; b2 += red[wv * 2 + 1]; }
    statp[c * 8 + slab] = make_float2(a, b2);
  }
}

__global__ void combine_kernel(const float2* __restrict__ statp,
                               const float* __restrict__ g,
                               const float* __restrict__ bb,
                               float2* __restrict__ bnp) {
  int c = threadIdx.x;
  if (c < 64) {
    float s1 = 0.f, s2 = 0.f;
    #pragma unroll
    for (int s = 0; s < 8; ++s) { float2 v = statp[c * 8 + s]; s1 += v.x; s2 += v.y; }
    float mu = s1 * (1.f / 8192.f);
    float var = s2 * (1.f / 8192.f) - mu * mu;
    float scale = g[c] * rsqrtf(var + 1e-5f);
    bnp[c] = make_float2(scale, bb[c] - mu * scale);
  }
}

// ---------------- BN apply (+optional skip) + leaky relu --------------------
template <int WITHSKIP>
__global__ __launch_bounds__(256) void bnapply_kernel(const float* __restrict__ rsum,
                                                      const float2* __restrict__ bnp,
                                                      const float* __restrict__ skip,
                                                      float* __restrict__ out) {
  int e = (blockIdx.x * 256 + threadIdx.x) << 2;
  int c = (e >> 12) & 63;
  float2 p = bnp[c];
  float4 v = *(const float4*)&rsum[e];
  float4 s = make_float4(0.f, 0.f, 0.f, 0.f);
  if (WITHSKIP) s = *(const float4*)&skip[e];
  float4 r;
  float u;
  u = v.x * p.x + p.y + s.x; r.x = u > 0.f ? u : 0.01f * u;
  u = v.y * p.x + p.y + s.y; r.y = u > 0.f ? u : 0.01f * u;
  u = v.z * p.x + p.y + s.z; r.z = u > 0.f ? u : 0.01f * u;
  u = v.w * p.x + p.y + s.w; r.w = u > 0.f ? u : 0.01f * u;
  *(float4*)&out[e] = r;
}

// ---------------------------------------------------------------------------
extern "C" void kernel_launch(void* const* d_in, const int* in_sizes, int n_in,
                              void* d_out, int out_size, void* d_ws, size_t ws_size,
                              hipStream_t stream) {
  (void)in_sizes; (void)n_in; (void)out_size; (void)ws_size;
  const float* x     = (const float*)d_in[0];
  const float* ln_g  = (const float*)d_in[1];
  const float* ln_b  = (const float*)d_in[2];
  const float* gamma = (const float*)d_in[3];
  const float* p1_w  = (const float*)d_in[4];
  const float* p1_b  = (const float*)d_in[5];
  const float* c0_w  = (const float*)d_in[6];
  const float* c0_b  = (const float*)d_in[7];
  const float* cs_w  = (const float*)d_in[8];
  const float* cs_b  = (const float*)d_in[9];
  const float* off_w = (const float*)d_in[10];
  const float* off_b = (const float*)d_in[11];
  const float* def_w = (const float*)d_in[12];
  const float* def_b = (const float*)d_in[13];
  const float* lk1_w = (const float*)d_in[14];
  const float* lk1_b = (const float*)d_in[15];
  const float* p2_w  = (const float*)d_in[16];
  const float* p2_b  = (const float*)d_in[17];
  const float* r1_w  = (const float*)d_in[18];
  const float* r1_b  = (const float*)d_in[19];
  const float* bn1_g = (const float*)d_in[20];
  const float* bn1_b = (const float*)d_in[21];
  const float* r2_w  = (const float*)d_in[22];
  const float* r2_b  = (const float*)d_in[23];
  const float* bn2_g = (const float*)d_in[24];
  const float* bn2_b = (const float*)d_in[25];
  const float* c8_w  = (const float*)d_in[26];
  const float* c8_b  = (const float*)d_in[27];
  float* outp = (float*)d_out;

  float* wsp = (float*)d_ws;
  size_t ofs = 0;
  auto alloc = [&](size_t n) { float* p = wsp + ofs; ofs += n; return p; };
  // NOTE: offparts must be immediately followed by parts8: the 8 offset-conv
  // slabs (5,308,416 floats) overflow into parts8's head, which is dead then.
  float* ybuf     = alloc(524288);   // LN out (shortcut); later reused as o1
  float* ubuf     = alloc(524288);   // gelu(p1); later reused as o3
  float* abuf     = alloc(524288);   // dw5 out
  float* a2       = alloc(524288);   // dw7 out (channel-major)
  float* a2cl     = alloc(524288);   // dw7 out (channel-last, via transpose)
  float* offparts = alloc(2654208);  // offset-conv partials slabs 0-3
  float* parts8   = alloc(4194304);  // slabs 4-7 overflow; deform partials; r1/r2 partials
  float* offcl    = alloc(663552);   // offsets (B,N,81)
  float* l1       = alloc(524288);   // lk1 out
  float* skipb    = alloc(524288);   // skip (B,C,N)
  float* rsum     = alloc(524288);   // reduced conv out
  float2* statp   = (float2*)alloc(1024);
  float2* bnp     = (float2*)alloc(128);
  float* wr1      = alloc(110592);
  float* wr2      = alloc(110592);
  float* wroff    = alloc(139968);
  float* wdd      = alloc(110592);
  float* dparts = parts8;            // deform partials (8 x 524288, exact fit)
  float* o1 = ybuf;
  float* o3 = ubuf;

  // weight repacks
  repackA_kernel<<<(110592 + 255) / 256, 256, 0, stream>>>(r1_w, wr1, 64, 110592);
  repackA_kernel<<<(110592 + 255) / 256, 256, 0, stream>>>(r2_w, wr2, 64, 110592);
  repackA_kernel<<<(139968 + 255) / 256, 256, 0, stream>>>(off_w, wroff, 81, 139968);
  repackB_kernel<<<(110592 + 255) / 256, 256, 0, stream>>>(def_w, wdd);

  // 1. LayerNorm
  ln_kernel<<<128, 64, 0, stream>>>(x, ln_g, ln_b, ybuf);
  // 2. p1 1x1 + gelu
  pw_kernel<0><<<128, 256, 0, stream>>>(ybuf, nullptr, nullptr, nullptr, p1_w, p1_b, nullptr, ubuf);
  // 3. depthwise 5^3
  dw5_kernel<<<128, 256, 0, stream>>>(ubuf, c0_w, c0_b, abuf);
  // 4. depthwise 7^3 dil3 (channel-major only), then LDS-tiled transpose
  dw7_kernel<<<128, 256, 0, stream>>>(abuf, cs_w, cs_b, a2);
  transpose_kernel<<<128, 256, 0, stream>>>(a2, a2cl);
  // 5. offset conv (64->81, 3^3) split-K 8 (slabs spill into dead parts8)
  conv3_kernel<81, 3, 27, 4, 128, 8><<<dim3(128, 8), 128, 0, stream>>>(a2, wroff, offparts);
  offreduce_kernel<<<128, 256, 0, stream>>>(offparts, off_b, offcl);
  // 6. deformable sampling + einsum, 256-thread blocks, 8 tap-groups
  deform_kernel<<<dim3(128, 8), 256, 0, stream>>>(a2cl, offcl, wdd, dparts);
  // 7. lk1 1x1 (stages sum of 8 deform partials + def_b)
  pw_kernel<1><<<128, 256, 0, stream>>>(dparts, def_b, nullptr, nullptr, lk1_w, lk1_b, nullptr, l1);
  // 8. p2 1x1 on u*l1, +shortcut, then skip = x + gamma*y9
  pw_kernel<2><<<128, 256, 0, stream>>>(ubuf, l1, ybuf, x, p2_w, p2_b, gamma, skipb);
  // 9. r1 3^3 conv split-K 8 (256-thread, OTILE=1) -> BN1 -> lrelu
  conv3_kernel<64, 1, 64, 4, 256, 8><<<dim3(128, 8), 256, 0, stream>>>(skipb, wr1, parts8);
  stats_kernel<<<dim3(64, 8), 256, 0, stream>>>(parts8, r1_b, rsum, statp);
  combine_kernel<<<1, 64, 0, stream>>>(statp, bn1_g, bn1_b, bnp);
  bnapply_kernel<0><<<512, 256, 0, stream>>>(rsum, bnp, nullptr, o1);
  // 10. r2 3^3 conv split-K 8 (256-thread, OTILE=1) -> BN2 -> (+skip) -> lrelu
  conv3_kernel<64, 1, 64, 4, 256, 8><<<dim3(128, 8), 256, 0, stream>>>(o1, wr2, parts8);
  stats_kernel<<<dim3(64, 8), 256, 0, stream>>>(parts8, r2_b, rsum, statp);
  combine_kernel<<<1, 64, 0, stream>>>(statp, bn2_g, bn2_b, bnp);
  bnapply_kernel<1><<<512, 256, 0, stream>>>(rsum, bnp, skipb, o3);
  // 11. final: out = skip + c8(o3)
  pw_kernel<3><<<128, 256, 0, stream>>>(o3, skipb, nullptr, nullptr, c8_w, c8_b, nullptr, outp);
}